// Round 6
// baseline (393.780 us; speedup 1.0000x reference)
//
#include <hip/hip_runtime.h>
#include <stdint.h>
#include <math.h>

// ---------------- types & helpers ----------------
typedef float    f32x4 __attribute__((ext_vector_type(4)));
typedef float    f32x2 __attribute__((ext_vector_type(2)));
typedef short    s16x8 __attribute__((ext_vector_type(8)));
typedef short    s16x4 __attribute__((ext_vector_type(4)));
typedef unsigned u32x2 __attribute__((ext_vector_type(2)));

#define SCALE_LOG2E 0.1803368751839806f   // 0.125 * log2(e)

__device__ __forceinline__ float bf2f(short s) {
  unsigned u = ((unsigned)(unsigned short)s) << 16;
  return __builtin_bit_cast(float, u);
}
__device__ __forceinline__ short f2bf(float f) {
  unsigned u = __builtin_bit_cast(unsigned, f);
  u = u + 0x7fffu + ((u >> 16) & 1u);   // RNE
  return (short)(u >> 16);
}
// pack two f32 -> two bf16 (RNE) in one instruction
__device__ __forceinline__ unsigned cvtpk(float lo, float hi) {
  unsigned r;
  asm("v_cvt_pk_bf16_f32 %0, %1, %2" : "=v"(r) : "v"(lo), "v"(hi));
  return r;
}
__device__ __forceinline__ void g2l16(const void* g, void* l) {
  __builtin_amdgcn_global_load_lds((const __attribute__((address_space(1))) void*)g,
                                   (__attribute__((address_space(3))) void*)l,
                                   16, 0, 0);
}
#define BARRIER() do { __builtin_amdgcn_s_barrier(); __builtin_amdgcn_sched_barrier(0); } while (0)
#define VMCNT(N)  asm volatile("s_waitcnt vmcnt(" #N ")" ::: "memory")
#define LGKM0()   do { asm volatile("s_waitcnt lgkmcnt(0)" ::: "memory"); __builtin_amdgcn_sched_barrier(0); } while (0)
#define MFMA(a, b, c)  __builtin_amdgcn_mfma_f32_16x16x32_bf16(a, b, c, 0, 0, 0)
#define MFMA8(a, b, c) __builtin_amdgcn_mfma_f32_16x16x32_fp8_fp8(a, b, c, 0, 0, 0)

// t-permutation within 32-blocks: t = nn*16+j -> j*2+nn (pairs C-frag cols for cvt_pk)
__device__ __forceinline__ int pi32(int t) {
  return (t & ~31) | ((t & 15) << 1) | ((t >> 4) & 1);
}

// ---------------- prep: transpose 1024x1024 f32 weights -> bf16 [N][K] ----------------
__global__ void wtrans_kernel(const float* __restrict__ Wq, const float* __restrict__ Wk,
                              const float* __restrict__ Wv, const float* __restrict__ Wd,
                              short* __restrict__ WqT, short* __restrict__ WkT,
                              short* __restrict__ WvT, short* __restrict__ WdT) {
  __shared__ float tile[64][65];
  const float* src; short* dst;
  switch (blockIdx.z) {
    case 0: src = Wq; dst = WqT; break;
    case 1: src = Wk; dst = WkT; break;
    case 2: src = Wv; dst = WvT; break;
    default: src = Wd; dst = WdT; break;
  }
  int k0 = blockIdx.y * 64;
  int n0 = blockIdx.x * 64;
  int tid = threadIdx.x;
#pragma unroll
  for (int p = 0; p < 4; ++p) {
    int idx = p * 1024 + tid * 4;
    int r = idx >> 6, c = idx & 63;
    f32x4 v = *(const f32x4*)(src + (size_t)(k0 + r) * 1024 + n0 + c);
    tile[r][c + 0] = v[0]; tile[r][c + 1] = v[1];
    tile[r][c + 2] = v[2]; tile[r][c + 3] = v[3];
  }
  __syncthreads();
#pragma unroll
  for (int p = 0; p < 2; ++p) {
    int idx = p * 2048 + tid * 8;
    int r = idx >> 6, c = idx & 63;
    s16x8 o;
#pragma unroll
    for (int i = 0; i < 8; ++i) o[i] = f2bf(tile[c + i][r]);
    *(s16x8*)(dst + (size_t)(n0 + r) * 1024 + k0 + c) = o;
  }
}

// Wcb -> WcbT bf16 [16][1024]; mixing -> bf16 scaled by SCALE_LOG2E*64 (fp8 pre-scale)
__global__ void smallconv_kernel(const float* __restrict__ Wcb, const float* __restrict__ mixing,
                                 short* __restrict__ WcbT, short* __restrict__ mixbf) {
  int idx = blockIdx.x * 256 + threadIdx.x;
  if (idx < 16384) {
    int h = idx >> 10, d = idx & 1023;
    WcbT[idx] = f2bf(Wcb[d * 16 + h]);
  } else {
    int j = idx - 16384;
    mixbf[j] = f2bf(mixing[j] * (SCALE_LOG2E * 64.0f));
  }
}

__global__ void gather_kernel(const float* __restrict__ hidden, const int* __restrict__ fpos,
                              const int* __restrict__ tpos, float* __restrict__ from_f,
                              short* __restrict__ from_bf, short* __restrict__ to_bf) {
  int row = blockIdx.x;
  int c = threadIdx.x * 4;
  if (blockIdx.y == 0) {
    int src = fpos[row] & 511;
    f32x4 v = *(const f32x4*)(hidden + (size_t)src * 1024 + c);
    *(f32x4*)(from_f + (size_t)row * 1024 + c) = v;
    s16x4 o;
#pragma unroll
    for (int i = 0; i < 4; ++i) o[i] = f2bf(v[i]);
    *(s16x4*)(from_bf + (size_t)row * 1024 + c) = o;
  } else {
    int src = tpos[row] & 511;
    f32x4 v = *(const f32x4*)(hidden + (size_t)src * 1024 + c);
    s16x4 o;
#pragma unroll
    for (int i = 0; i < 4; ++i) o[i] = f2bf(v[i]);
    *(s16x4*)(to_bf + (size_t)row * 1024 + c) = o;
  }
}

// ---------------- merged QKV GEMM (z: 0=q swz, 1=k swz, 2=v transposed + pi + swz) ----------
__global__ __launch_bounds__(256, 2)
void qkv_gemm(const short* __restrict__ from_bf, const short* __restrict__ to_bf,
              const short* __restrict__ WqT, const short* __restrict__ WkT,
              const short* __restrict__ WvT, const float* __restrict__ bv,
              short* __restrict__ q_swz, short* __restrict__ k_swz, short* __restrict__ vTs) {
  __shared__ __align__(16) short As[128][64];
  __shared__ __align__(16) short Bs[128][64];
  int mode = blockIdx.z;
  const short* A = (mode == 0) ? from_bf : to_bf;
  const short* B = (mode == 0) ? WqT : (mode == 1) ? WkT : WvT;
  int m0 = blockIdx.x * 128, n0 = blockIdx.y * 128;
  int tid = threadIdx.x;
  int w = tid >> 6, l = tid & 63;
  int wr = w >> 1, wc = w & 1;
  f32x4 acc[4][4] = {};
  for (int k0 = 0; k0 < 1024; k0 += 64) {
    __syncthreads();
#pragma unroll
    for (int i = 0; i < 4; ++i) {
      int off = i * 4096 + tid * 16;
      int r = off >> 7, cb_ = off & 127;
      g2l16(A + ((size_t)(m0 + r) << 10) + k0 + (cb_ >> 1), (short*)As + (off >> 1));
      g2l16(B + ((size_t)(n0 + r) << 10) + k0 + (cb_ >> 1), (short*)Bs + (off >> 1));
    }
    __syncthreads();
#pragma unroll
    for (int ks = 0; ks < 2; ++ks) {
      s16x8 af[4], bfr[4];
#pragma unroll
      for (int m = 0; m < 4; ++m)
        af[m] = *(const s16x8*)&As[wr * 64 + m * 16 + (l & 15)][ks * 32 + (l >> 4) * 8];
#pragma unroll
      for (int n = 0; n < 4; ++n)
        bfr[n] = *(const s16x8*)&Bs[wc * 64 + n * 16 + (l & 15)][ks * 32 + (l >> 4) * 8];
#pragma unroll
      for (int m = 0; m < 4; ++m)
#pragma unroll
        for (int n = 0; n < 4; ++n)
          acc[m][n] = MFMA(af[m], bfr[n], acc[m][n]);
    }
  }
  int lr = (l >> 4) * 4, lc = l & 15;
#pragma unroll
  for (int m = 0; m < 4; ++m)
#pragma unroll
    for (int n = 0; n < 4; ++n) {
      int row = m0 + wr * 64 + m * 16 + lr;
      int col = n0 + wc * 64 + n * 16 + lc;
      if (mode == 0) {
#pragma unroll
        for (int r = 0; r < 4; ++r) {
          int rr = row + r;
          q_swz[(size_t)rr * 1024 + (col ^ ((rr & 7) << 3))] = f2bf(acc[m][n][r]);
        }
      } else if (mode == 1) {
#pragma unroll
        for (int r = 0; r < 4; ++r) {
          int rr = row + r;
          k_swz[(size_t)rr * 1024 + (col ^ ((rr & 7) << 3))] = f2bf(acc[m][n][r]);
        }
      } else {
        float b = bv[col];
#pragma unroll
        for (int r = 0; r < 4; ++r) {
          int rr = row + r;                              // t index
          int tsw = pi32(rr) ^ ((col & 7) << 3);         // pi permutation + XOR swizzle
          vTs[(size_t)col * 2048 + tsw] = f2bf(acc[m][n][r] + b);
        }
      }
    }
}

// k_swz bf16 -> fp8 e4m3 (x4 pre-scale), same swizzled positions (byte==elem granularity)
__global__ void k8_kernel(const short* __restrict__ k_swz, unsigned char* __restrict__ k8) {
  int gid = blockIdx.x * 256 + threadIdx.x;        // 2048*128
  int row = gid >> 7, c = (gid & 127) * 8;
  s16x8 v = *(const s16x8*)(k_swz + ((size_t)row << 10) + c);
  unsigned lo = 0, hi = 0;
  lo = __builtin_amdgcn_cvt_pk_fp8_f32(bf2f(v[0]) * 4.f, bf2f(v[1]) * 4.f, lo, false);
  lo = __builtin_amdgcn_cvt_pk_fp8_f32(bf2f(v[2]) * 4.f, bf2f(v[3]) * 4.f, lo, true);
  hi = __builtin_amdgcn_cvt_pk_fp8_f32(bf2f(v[4]) * 4.f, bf2f(v[5]) * 4.f, hi, false);
  hi = __builtin_amdgcn_cvt_pk_fp8_f32(bf2f(v[6]) * 4.f, bf2f(v[7]) * 4.f, hi, true);
  u32x2 o; o[0] = lo; o[1] = hi;
  *(u32x2*)(k8 + ((size_t)row << 10) + c) = o;
}

// qm8[h][f][c] = q_swz[f][c] * mixbf[h][c ^ 8*(f&7)]  (fp8; mixbf carries SCALE*64)
__global__ void qmix8_kernel(const short* __restrict__ q_swz, const short* __restrict__ mixbf,
                             unsigned char* __restrict__ qm8) {
  int f = blockIdx.x, h = blockIdx.y;
  int c = threadIdx.x * 8;
  int fs = (f & 7) << 3;
  s16x8 qv = *(const s16x8*)(q_swz + ((size_t)f << 10) + c);
  s16x8 mv = *(const s16x8*)(mixbf + ((size_t)h << 10) + (c ^ fs));
  float p[8];
#pragma unroll
  for (int i = 0; i < 8; ++i) p[i] = bf2f(qv[i]) * bf2f(mv[i]);
  unsigned lo = 0, hi = 0;
  lo = __builtin_amdgcn_cvt_pk_fp8_f32(p[0], p[1], lo, false);
  lo = __builtin_amdgcn_cvt_pk_fp8_f32(p[2], p[3], lo, true);
  hi = __builtin_amdgcn_cvt_pk_fp8_f32(p[4], p[5], hi, false);
  hi = __builtin_amdgcn_cvt_pk_fp8_f32(p[6], p[7], hi, true);
  u32x2 o; o[0] = lo; o[1] = hi;
  *(u32x2*)(qm8 + (((size_t)h * 2048 + f) << 10) + c) = o;
}

// ---------------- content bias (pre-scaled by SCALE_LOG2E) ----------------
__global__ void cb_kernel(const short* __restrict__ to_bf, const short* __restrict__ WcbT,
                          float* __restrict__ cbv) {
  __shared__ short Wl[16 * 1024];
  int tid = threadIdx.x;
  for (int i = tid; i < 2048; i += 256)
    ((s16x8*)Wl)[i] = ((const s16x8*)WcbT)[i];
  __syncthreads();
  int w = tid >> 6, l = tid & 63;
  int t = blockIdx.x * 4 + w;
  const s16x8* xr = (const s16x8*)(to_bf + ((size_t)t << 10) + l * 16);
  s16x8 x0 = xr[0], x1 = xr[1];
  float xf[16];
#pragma unroll
  for (int i = 0; i < 8; ++i) { xf[i] = bf2f(x0[i]); xf[8 + i] = bf2f(x1[i]); }
#pragma unroll
  for (int h = 0; h < 16; ++h) {
    const s16x8* wr_ = (const s16x8*)(Wl + h * 1024 + l * 16);
    s16x8 w0 = wr_[0], w1 = wr_[1];
    float acc = 0.f;
#pragma unroll
    for (int i = 0; i < 8; ++i) { acc += xf[i] * bf2f(w0[i]); acc += xf[8 + i] * bf2f(w1[i]); }
#pragma unroll
    for (int s = 32; s; s >>= 1) acc += __shfl_xor(acc, s);
    if (l == 0) cbv[(size_t)h * 2048 + t] = acc * SCALE_LOG2E;
  }
}

// ---------------- flash attention v6: fp8 QK^T, 8 waves, FBLK=256, TBLK=128, ts=4 -----------
// LDS 66KB: qmA@0(16K fp8 [256f][64B]) qmB@16K ktA@32K(8K [128t][64B]) ktB@40K
//           vt@48K(16K bf16 [64dh][256B]) cbl@64K(2K f32)
// P (bf16, pi-permuted t) overlays qmB: 2KB/wave, PV in 4 quarters of 32 t.
__global__ __launch_bounds__(512, 4)
void attn_kernel(const unsigned char* __restrict__ qm8, const unsigned char* __restrict__ k8,
                 const short* __restrict__ vTs, const float* __restrict__ cbg,
                 float* __restrict__ ctxp, f32x2* __restrict__ mlb) {
  __shared__ __align__(16) char smem[67584];
  char* qmA = smem;          char* qmB = smem + 16384;
  char* ktA = smem + 32768;  char* ktB = smem + 40960;
  char* vt  = smem + 49152;
  float* cbl = (float*)(smem + 65536);
  const int f0 = blockIdx.x * 256, h = blockIdx.y, ts = blockIdx.z;
  const int tb = ts << 9;                       // 512 t per split
  const int tid = threadIdx.x, w = tid >> 6, l = tid & 63;
  const int lr = l >> 4, lc = l & 15;
  const int swz8 = (lc & 7) << 3;
  cbl[tid & 511] = cbg[h * 2048 + tb + (tid & 511)];
  const unsigned char* qbase = qm8 + (((size_t)h * 2048 + f0) << 10);

#define ISSUE_QK(qmb, ktb, k0e, trow0)                                                      \
  do {                                                                                      \
    _Pragma("unroll") for (int i_ = 0; i_ < 2; ++i_) {                                      \
      int off_ = i_ * 8192 + tid * 16;                                                      \
      g2l16(qbase + ((size_t)(off_ >> 6) << 10) + (k0e) + (off_ & 63), (qmb) + off_);       \
    }                                                                                       \
    {                                                                                       \
      int off_ = tid * 16;                                                                  \
      g2l16(k8 + ((size_t)((trow0) + (off_ >> 6)) << 10) + (k0e) + (off_ & 63),             \
            (ktb) + off_);                                                                  \
    }                                                                                       \
  } while (0)

  ISSUE_QK(qmA, ktA, 0, tb);                    // prologue: chunk 0 of t0=0

  float m_run[8], l_run[8];
#pragma unroll
  for (int s2 = 0; s2 < 8; ++s2) { m_run[s2] = -1e30f; l_run[s2] = 0.f; }
  f32x4 ctx[2][4] = {};

  for (int t0 = 0; t0 < 512; t0 += 128) {
    // V tile (2 loads)
#pragma unroll
    for (int i = 0; i < 2; ++i) {
      int off = i * 8192 + tid * 16;
      g2l16(vTs + (((size_t)(h * 64 + (off >> 8))) << 11) + tb + t0 + ((off & 255) >> 1),
            vt + off);
    }
    f32x4 sacc[2][8] = {};
    for (int c = 0; c < 16; ++c) {
      char* qmb = (c & 1) ? qmB : qmA;
      char* ktb = (c & 1) ? ktB : ktA;
      if (c < 15) {
        ISSUE_QK((c & 1) ? qmA : qmB, (c & 1) ? ktA : ktB, (c + 1) * 64, tb + t0);
      } else if (t0 < 384) {
        ISSUE_QK(qmA, ktA, 0, tb + t0 + 128);
      }
      if (c == 0) { VMCNT(5); }
      else if (c == 15 && t0 == 384) { VMCNT(0); }
      else { VMCNT(3); }
      BARRIER();
#pragma unroll
      for (int ks = 0; ks < 2; ++ks) {
        int xr = (ks * 32 + lr * 8) ^ swz8;
        long af0 = *(const long*)(qmb + ((w * 32 + lc) << 6) + xr);
        long af1 = *(const long*)(qmb + ((w * 32 + 16 + lc) << 6) + xr);
        __builtin_amdgcn_s_setprio(1);
#pragma unroll
        for (int n = 0; n < 8; ++n) {
          long bfr = *(const long*)(ktb + ((n * 16 + lc) << 6) + xr);
          sacc[0][n] = MFMA8(af0, bfr, sacc[0][n]);
          sacc[1][n] = MFMA8(af1, bfr, sacc[1][n]);
        }
        __builtin_amdgcn_s_setprio(0);
      }
      BARRIER();
    }
    // ---- online softmax, exp2 domain; descale 2^-8 fused into the cb add (fma)
    float pm[8];
#pragma unroll
    for (int s2 = 0; s2 < 8; ++s2) pm[s2] = -1e30f;
#pragma unroll
    for (int m = 0; m < 2; ++m)
#pragma unroll
      for (int n = 0; n < 8; ++n) {
        float cbv = cbl[t0 + n * 16 + lc];
#pragma unroll
        for (int r = 0; r < 4; ++r) {
          float s = fmaf(sacc[m][n][r], 0.00390625f, cbv);
          sacc[m][n][r] = s;
          pm[m * 4 + r] = fmaxf(pm[m * 4 + r], s);
        }
      }
#pragma unroll
    for (int s_ = 1; s_ < 16; s_ <<= 1)
#pragma unroll
      for (int s2 = 0; s2 < 8; ++s2) pm[s2] = fmaxf(pm[s2], __shfl_xor(pm[s2], s_));
    float tsum[8];
#pragma unroll
    for (int s2 = 0; s2 < 8; ++s2) {
      float mnew = fmaxf(m_run[s2], pm[s2]);
      float corr = exp2f(m_run[s2] - mnew);
      m_run[s2] = mnew; l_run[s2] *= corr; tsum[s2] = 0.f;
      int m = s2 >> 2, r = s2 & 3;
#pragma unroll
      for (int n2 = 0; n2 < 4; ++n2) ctx[m][n2][r] *= corr;
    }
#pragma unroll
    for (int m = 0; m < 2; ++m)
#pragma unroll
      for (int n = 0; n < 8; ++n)
#pragma unroll
        for (int r = 0; r < 4; ++r) {
          float e = exp2f(sacc[m][n][r] - m_run[m * 4 + r]);
          sacc[m][n][r] = e;
          tsum[m * 4 + r] += e;
        }
#pragma unroll
    for (int s_ = 1; s_ < 16; s_ <<= 1)
#pragma unroll
      for (int s2 = 0; s2 < 8; ++s2) tsum[s2] += __shfl_xor(tsum[s2], s_);
#pragma unroll
    for (int s2 = 0; s2 < 8; ++s2) l_run[s2] += tsum[s2];
    // ---- P (paired cvt_pk, pi-ordered t) + PV in 4 quarters of 32 t
    char* ptw = qmB + (w << 11);               // 2KB/wave: [32f][64B = 32 t' x bf16]
#pragma unroll
    for (int qq = 0; qq < 4; ++qq) {
      if (qq) { LGKM0(); }                     // prior quarter's reads done before overwrite
#pragma unroll
      for (int m = 0; m < 2; ++m)
#pragma unroll
        for (int r = 0; r < 4; ++r) {
          int row = m * 16 + lr * 4 + r;
          unsigned pk = cvtpk(sacc[m][2 * qq][r], sacc[m][2 * qq + 1][r]);
          *(unsigned*)(ptw + (row << 6) + ((lc << 2) ^ ((row & 3) << 4))) = pk;
        }
      LGKM0();
      s16x8 paf0 = *(const s16x8*)(ptw + (lc << 6) + ((lr * 16) ^ ((lc & 3) << 4)));
      s16x8 paf1 = *(const s16x8*)(ptw + ((16 + lc) << 6) + ((lr * 16) ^ ((lc & 3) << 4)));
#pragma unroll
      for (int n2 = 0; n2 < 4; ++n2) {
        s16x8 vb = *(const s16x8*)(vt + ((n2 * 16 + lc) << 8) +
                                   ((qq * 64 + lr * 16) ^ ((lc & 7) << 4)));
        ctx[0][n2] = MFMA(paf0, vb, ctx[0][n2]);
        ctx[1][n2] = MFMA(paf1, vb, ctx[1][n2]);
      }
    }
    BARRIER();   // protect vt + P region before next t0's staging writes
  }
  // ---- write partials
  const int pb = (h * 4 + ts) * 2048;
#pragma unroll
  for (int m = 0; m < 2; ++m)
#pragma unroll
    for (int n2 = 0; n2 < 4; ++n2)
#pragma unroll
      for (int r = 0; r < 4; ++r) {
        int f = f0 + w * 32 + m * 16 + lr * 4 + r;
        ctxp[((size_t)(pb + f) << 6) + n2 * 16 + lc] = ctx[m][n2][r];
      }
  if (lc == 0) {
#pragma unroll
    for (int s2 = 0; s2 < 8; ++s2) {
      int f = f0 + w * 32 + (s2 >> 2) * 16 + lr * 4 + (s2 & 3);
      f32x2 v; v[0] = m_run[s2]; v[1] = l_run[s2];
      mlb[pb + f] = v;
    }
  }
#undef ISSUE_QK
}

// ---------------- combine the 4 t-split partials (exp2 domain) ----------------
__global__ void combine_kernel(const float* __restrict__ ctxp, const f32x2* __restrict__ mlb,
                               short* __restrict__ ctx_bf) {
  int f = blockIdx.x, tid = threadIdx.x;
  int h = tid >> 4, d4 = (tid & 15) * 4;
  f32x2 ml[4];
  float mx = -1e30f;
#pragma unroll
  for (int p = 0; p < 4; ++p) {
    ml[p] = mlb[(h * 4 + p) * 2048 + f];
    mx = fmaxf(mx, ml[p][0]);
  }
  float e[4], L = 0.f;
#pragma unroll
  for (int p = 0; p < 4; ++p) { e[p] = exp2f(ml[p][0] - mx); L += ml[p][1] * e[p]; }
  float inv = 1.f / L;
  f32x4 s = {};
#pragma unroll
  for (int p = 0; p < 4; ++p) {
    f32x4 cp = *(const f32x4*)(ctxp + (((size_t)(h * 4 + p) * 2048 + f) << 6) + d4);
#pragma unroll
    for (int i = 0; i < 4; ++i) s[i] += cp[i] * e[p];
  }
  s16x4 o;
#pragma unroll
  for (int i = 0; i < 4; ++i) o[i] = f2bf(s[i] * inv);
  *(s16x4*)(ctx_bf + ((size_t)f << 10) + h * 64 + d4) = o;
}

// ---------------- final GEMM: C f32 = ctx @ WdT + bd + resid ----------------
__global__ __launch_bounds__(256, 2)
void gemm_out(const short* __restrict__ A, const short* __restrict__ B,
              const float* __restrict__ bias, const float* __restrict__ resid,
              float* __restrict__ Cout) {
  __shared__ __align__(16) short As[128][64];
  __shared__ __align__(16) short Bs[128][64];
  int m0 = blockIdx.x * 128, n0 = blockIdx.y * 128;
  int tid = threadIdx.x;
  int w = tid >> 6, l = tid & 63;
  int wr = w >> 1, wc = w & 1;
  f32x4 acc[4][4] = {};
  for (int k0 = 0; k0 < 1024; k0 += 64) {
    __syncthreads();
#pragma unroll
    for (int i = 0; i < 4; ++i) {
      int off = i * 4096 + tid * 16;
      int r = off >> 7, cb_ = off & 127;
      g2l16(A + ((size_t)(m0 + r) << 10) + k0 + (cb_ >> 1), (short*)As + (off >> 1));
      g2l16(B + ((size_t)(n0 + r) << 10) + k0 + (cb_ >> 1), (short*)Bs + (off >> 1));
    }
    __syncthreads();
#pragma unroll
    for (int ks = 0; ks < 2; ++ks) {
      s16x8 af[4], bfr[4];
#pragma unroll
      for (int m = 0; m < 4; ++m)
        af[m] = *(const s16x8*)&As[wr * 64 + m * 16 + (l & 15)][ks * 32 + (l >> 4) * 8];
#pragma unroll
      for (int n = 0; n < 4; ++n)
        bfr[n] = *(const s16x8*)&Bs[wc * 64 + n * 16 + (l & 15)][ks * 32 + (l >> 4) * 8];
#pragma unroll
      for (int m = 0; m < 4; ++m)
#pragma unroll
        for (int n = 0; n < 4; ++n)
          acc[m][n] = MFMA(af[m], bfr[n], acc[m][n]);
    }
  }
  int lr = (l >> 4) * 4, lc = l & 15;
#pragma unroll
  for (int m = 0; m < 4; ++m)
#pragma unroll
    for (int n = 0; n < 4; ++n) {
      int row = m0 + wr * 64 + m * 16 + lr;
      int col = n0 + wc * 64 + n * 16 + lc;
      float b = bias[col];
#pragma unroll
      for (int r = 0; r < 4; ++r)
        Cout[(size_t)(row + r) * 1024 + col] = acc[m][n][r] + b + resid[(size_t)(row + r) * 1024 + col];
    }
}

// ---------------- LayerNorm (in-place) ----------------
__global__ void ln_kernel(const float* __restrict__ res, const float* __restrict__ gamma,
                          const float* __restrict__ beta, float* __restrict__ out) {
  int row = blockIdx.x, tid = threadIdx.x;
  f32x4 x = *(const f32x4*)(res + ((size_t)row << 10) + tid * 4);
  float s = x[0] + x[1] + x[2] + x[3];
  float s2 = x[0] * x[0] + x[1] * x[1] + x[2] * x[2] + x[3] * x[3];
#pragma unroll
  for (int m = 1; m < 64; m <<= 1) { s += __shfl_xor(s, m); s2 += __shfl_xor(s2, m); }
  __shared__ float red[8];
  int w = tid >> 6, l = tid & 63;
  if (l == 0) { red[w] = s; red[4 + w] = s2; }
  __syncthreads();
  s = red[0] + red[1] + red[2] + red[3];
  s2 = red[4] + red[5] + red[6] + red[7];
  float mu = s * (1.f / 1024.f);
  float var = s2 * (1.f / 1024.f) - mu * mu;
  float rstd = rsqrtf(var + 1e-5f);
  f32x4 o;
#pragma unroll
  for (int i = 0; i < 4; ++i)
    o[i] = (x[i] - mu) * rstd * gamma[tid * 4 + i] + beta[tid * 4 + i];
  *(f32x4*)(out + ((size_t)row << 10) + tid * 4) = o;
}

// ---------------- launch ----------------
extern "C" void kernel_launch(void* const* d_in, const int* in_sizes, int n_in,
                              void* d_out, int out_size, void* d_ws, size_t ws_size,
                              hipStream_t stream) {
  const float* hidden = (const float*)d_in[0];
  const int*   fpos   = (const int*)d_in[1];
  const int*   tpos   = (const int*)d_in[2];
  const float* Wq     = (const float*)d_in[3];
  const float* Wk     = (const float*)d_in[4];
  const float* Wcb    = (const float*)d_in[5];
  const float* Wv     = (const float*)d_in[6];
  const float* bv     = (const float*)d_in[7];
  const float* mixing = (const float*)d_in[8];
  const float* Wd     = (const float*)d_in[9];
  const float* bd     = (const float*)d_in[10];
  const float* gamma  = (const float*)d_in[11];
  const float* beta   = (const float*)d_in[12];

  char* p = (char*)d_ws;
  auto alloc = [&](size_t bytes) { char* r = p; p += (bytes + 255) & ~(size_t)255; return r; };
  float* from_f  = (float*)alloc((size_t)2048 * 1024 * 4);
  short* from_bf = (short*)alloc((size_t)2048 * 1024 * 2);
  short* to_bf   = (short*)alloc((size_t)2048 * 1024 * 2);
  short* WqT     = (short*)alloc((size_t)1024 * 1024 * 2);
  short* WkT     = (short*)alloc((size_t)1024 * 1024 * 2);
  short* WvT     = (short*)alloc((size_t)1024 * 1024 * 2);
  short* WdT     = (short*)alloc((size_t)1024 * 1024 * 2);
  short* WcbT    = (short*)alloc((size_t)16 * 1024 * 2);
  short* mixbf   = (short*)alloc((size_t)16 * 1024 * 2);
  short* q_swz   = (short*)alloc((size_t)2048 * 1024 * 2);
  short* k_swz   = (short*)alloc((size_t)2048 * 1024 * 2);
  short* vTs     = (short*)alloc((size_t)1024 * 2048 * 2);
  unsigned char* k8  = (unsigned char*)alloc((size_t)2048 * 1024);
  unsigned char* qm8 = (unsigned char*)alloc((size_t)16 * 2048 * 1024);
  float* cbb     = (float*)alloc((size_t)16 * 2048 * 4);
  short* ctx_bf  = (short*)alloc((size_t)2048 * 1024 * 2);
  float* ctxp    = (float*)alloc((size_t)64 * 2048 * 64 * 4);
  f32x2* mlb     = (f32x2*)alloc((size_t)64 * 2048 * 8);

  wtrans_kernel<<<dim3(16, 16, 4), 256, 0, stream>>>(Wq, Wk, Wv, Wd, WqT, WkT, WvT, WdT);
  smallconv_kernel<<<128, 256, 0, stream>>>(Wcb, mixing, WcbT, mixbf);
  gather_kernel<<<dim3(2048, 2), 256, 0, stream>>>(hidden, fpos, tpos, from_f, from_bf, to_bf);
  qkv_gemm<<<dim3(16, 8, 3), 256, 0, stream>>>(from_bf, to_bf, WqT, WkT, WvT, bv,
                                               q_swz, k_swz, vTs);
  k8_kernel<<<1024, 256, 0, stream>>>(k_swz, k8);
  cb_kernel<<<512, 256, 0, stream>>>(to_bf, WcbT, cbb);
  qmix8_kernel<<<dim3(2048, 16), 128, 0, stream>>>(q_swz, mixbf, qm8);
  attn_kernel<<<dim3(8, 16, 4), 512, 0, stream>>>(qm8, k8, vTs, cbb, ctxp, mlb);
  combine_kernel<<<2048, 256, 0, stream>>>(ctxp, mlb, ctx_bf);
  gemm_out<<<dim3(16, 8), 256, 0, stream>>>(ctx_bf, WdT, bd, from_f, (float*)d_out);
  ln_kernel<<<2048, 256, 0, stream>>>((float*)d_out, gamma, beta, (float*)d_out);
}

// Round 7
// 349.499 us; speedup vs baseline: 1.1267x; 1.1267x over previous
//
#include <hip/hip_runtime.h>
#include <stdint.h>
#include <math.h>

// ---------------- types & helpers ----------------
typedef float    f32x4 __attribute__((ext_vector_type(4)));
typedef float    f32x2 __attribute__((ext_vector_type(2)));
typedef short    s16x8 __attribute__((ext_vector_type(8)));
typedef short    s16x4 __attribute__((ext_vector_type(4)));
typedef unsigned u32x2 __attribute__((ext_vector_type(2)));

#define SCALE_LOG2E 0.1803368751839806f   // 0.125 * log2(e)

__device__ __forceinline__ float bf2f(short s) {
  unsigned u = ((unsigned)(unsigned short)s) << 16;
  return __builtin_bit_cast(float, u);
}
__device__ __forceinline__ short f2bf(float f) {
  unsigned u = __builtin_bit_cast(unsigned, f);
  u = u + 0x7fffu + ((u >> 16) & 1u);   // RNE
  return (short)(u >> 16);
}
__device__ __forceinline__ unsigned cvtpk(float lo, float hi) {
  unsigned r;
  asm("v_cvt_pk_bf16_f32 %0, %1, %2" : "=v"(r) : "v"(lo), "v"(hi));
  return r;
}
__device__ __forceinline__ void g2l16(const void* g, void* l) {
  __builtin_amdgcn_global_load_lds((const __attribute__((address_space(1))) void*)g,
                                   (__attribute__((address_space(3))) void*)l,
                                   16, 0, 0);
}
#define BARRIER() do { __builtin_amdgcn_s_barrier(); __builtin_amdgcn_sched_barrier(0); } while (0)
#define VMCNT(N)  asm volatile("s_waitcnt vmcnt(" #N ")" ::: "memory")
#define LGKM0()   do { asm volatile("s_waitcnt lgkmcnt(0)" ::: "memory"); __builtin_amdgcn_sched_barrier(0); } while (0)
#define MFMA(a, b, c)  __builtin_amdgcn_mfma_f32_16x16x32_bf16(a, b, c, 0, 0, 0)
#define MFMA8(a, b, c) __builtin_amdgcn_mfma_f32_16x16x32_fp8_fp8(a, b, c, 0, 0, 0)

// t-permutation within 32-blocks: t = nn*16+j -> j*2+nn (pairs C-frag cols for cvt_pk)
__device__ __forceinline__ int pi32(int t) {
  return (t & ~31) | ((t & 15) << 1) | ((t >> 4) & 1);
}

// ---------------- prep: transpose 1024x1024 f32 weights -> bf16 [N][K] ----------------
__global__ void wtrans_kernel(const float* __restrict__ Wq, const float* __restrict__ Wk,
                              const float* __restrict__ Wv, const float* __restrict__ Wd,
                              short* __restrict__ WqT, short* __restrict__ WkT,
                              short* __restrict__ WvT, short* __restrict__ WdT) {
  __shared__ float tile[64][65];
  const float* src; short* dst;
  switch (blockIdx.z) {
    case 0: src = Wq; dst = WqT; break;
    case 1: src = Wk; dst = WkT; break;
    case 2: src = Wv; dst = WvT; break;
    default: src = Wd; dst = WdT; break;
  }
  int k0 = blockIdx.y * 64;
  int n0 = blockIdx.x * 64;
  int tid = threadIdx.x;
#pragma unroll
  for (int p = 0; p < 4; ++p) {
    int idx = p * 1024 + tid * 4;
    int r = idx >> 6, c = idx & 63;
    f32x4 v = *(const f32x4*)(src + (size_t)(k0 + r) * 1024 + n0 + c);
    tile[r][c + 0] = v[0]; tile[r][c + 1] = v[1];
    tile[r][c + 2] = v[2]; tile[r][c + 3] = v[3];
  }
  __syncthreads();
#pragma unroll
  for (int p = 0; p < 2; ++p) {
    int idx = p * 2048 + tid * 8;
    int r = idx >> 6, c = idx & 63;
    s16x8 o;
#pragma unroll
    for (int i = 0; i < 8; ++i) o[i] = f2bf(tile[c + i][r]);
    *(s16x8*)(dst + (size_t)(n0 + r) * 1024 + k0 + c) = o;
  }
}

// Wcb -> WcbT bf16 [16][1024]; mixing -> bf16 scaled by SCALE_LOG2E*64 (fp8 pre-scale)
__global__ void smallconv_kernel(const float* __restrict__ Wcb, const float* __restrict__ mixing,
                                 short* __restrict__ WcbT, short* __restrict__ mixbf) {
  int idx = blockIdx.x * 256 + threadIdx.x;
  if (idx < 16384) {
    int h = idx >> 10, d = idx & 1023;
    WcbT[idx] = f2bf(Wcb[d * 16 + h]);
  } else {
    int j = idx - 16384;
    mixbf[j] = f2bf(mixing[j] * (SCALE_LOG2E * 64.0f));
  }
}

__global__ void gather_kernel(const float* __restrict__ hidden, const int* __restrict__ fpos,
                              const int* __restrict__ tpos, float* __restrict__ from_f,
                              short* __restrict__ from_bf, short* __restrict__ to_bf) {
  int row = blockIdx.x;
  int c = threadIdx.x * 4;
  if (blockIdx.y == 0) {
    int src = fpos[row] & 511;
    f32x4 v = *(const f32x4*)(hidden + (size_t)src * 1024 + c);
    *(f32x4*)(from_f + (size_t)row * 1024 + c) = v;
    s16x4 o;
#pragma unroll
    for (int i = 0; i < 4; ++i) o[i] = f2bf(v[i]);
    *(s16x4*)(from_bf + (size_t)row * 1024 + c) = o;
  } else {
    int src = tpos[row] & 511;
    f32x4 v = *(const f32x4*)(hidden + (size_t)src * 1024 + c);
    s16x4 o;
#pragma unroll
    for (int i = 0; i < 4; ++i) o[i] = f2bf(v[i]);
    *(s16x4*)(to_bf + (size_t)row * 1024 + c) = o;
  }
}

// ---------------- merged QKV GEMM (z: 0=q plain, 1=k plain, 2=v transposed + pi + swz) ------
__global__ __launch_bounds__(256, 2)
void qkv_gemm(const short* __restrict__ from_bf, const short* __restrict__ to_bf,
              const short* __restrict__ WqT, const short* __restrict__ WkT,
              const short* __restrict__ WvT, const float* __restrict__ bv,
              short* __restrict__ q_bf, short* __restrict__ k_bf, short* __restrict__ vTs) {
  __shared__ __align__(16) short As[128][64];
  __shared__ __align__(16) short Bs[128][64];
  int mode = blockIdx.z;
  const short* A = (mode == 0) ? from_bf : to_bf;
  const short* B = (mode == 0) ? WqT : (mode == 1) ? WkT : WvT;
  int m0 = blockIdx.x * 128, n0 = blockIdx.y * 128;
  int tid = threadIdx.x;
  int w = tid >> 6, l = tid & 63;
  int wr = w >> 1, wc = w & 1;
  f32x4 acc[4][4] = {};
  for (int k0 = 0; k0 < 1024; k0 += 64) {
    __syncthreads();
#pragma unroll
    for (int i = 0; i < 4; ++i) {
      int off = i * 4096 + tid * 16;
      int r = off >> 7, cb_ = off & 127;
      g2l16(A + ((size_t)(m0 + r) << 10) + k0 + (cb_ >> 1), (short*)As + (off >> 1));
      g2l16(B + ((size_t)(n0 + r) << 10) + k0 + (cb_ >> 1), (short*)Bs + (off >> 1));
    }
    __syncthreads();
#pragma unroll
    for (int ks = 0; ks < 2; ++ks) {
      s16x8 af[4], bfr[4];
#pragma unroll
      for (int m = 0; m < 4; ++m)
        af[m] = *(const s16x8*)&As[wr * 64 + m * 16 + (l & 15)][ks * 32 + (l >> 4) * 8];
#pragma unroll
      for (int n = 0; n < 4; ++n)
        bfr[n] = *(const s16x8*)&Bs[wc * 64 + n * 16 + (l & 15)][ks * 32 + (l >> 4) * 8];
#pragma unroll
      for (int m = 0; m < 4; ++m)
#pragma unroll
        for (int n = 0; n < 4; ++n)
          acc[m][n] = MFMA(af[m], bfr[n], acc[m][n]);
    }
  }
  int lr = (l >> 4) * 4, lc = l & 15;
#pragma unroll
  for (int m = 0; m < 4; ++m)
#pragma unroll
    for (int n = 0; n < 4; ++n) {
      int row = m0 + wr * 64 + m * 16 + lr;
      int col = n0 + wc * 64 + n * 16 + lc;
      if (mode == 0) {
#pragma unroll
        for (int r = 0; r < 4; ++r) q_bf[(size_t)(row + r) * 1024 + col] = f2bf(acc[m][n][r]);
      } else if (mode == 1) {
#pragma unroll
        for (int r = 0; r < 4; ++r) k_bf[(size_t)(row + r) * 1024 + col] = f2bf(acc[m][n][r]);
      } else {
        float b = bv[col];
#pragma unroll
        for (int r = 0; r < 4; ++r) {
          int rr = row + r;                              // t index
          int tsw = pi32(rr) ^ ((col & 7) << 3);         // pi permutation + XOR swizzle
          vTs[(size_t)col * 2048 + tsw] = f2bf(acc[m][n][r] + b);
        }
      }
    }
}

// k bf16 -> fp8 e4m3 (x4 pre-scale), 128B rows with 4-bit row-key swizzle on 8-elem granules
__global__ void k8_kernel(const short* __restrict__ k_bf, unsigned char* __restrict__ k8) {
  int gid = blockIdx.x * 256 + threadIdx.x;        // 2048 rows * 128 granules
  int row = gid >> 7, c = (gid & 127) * 8;
  s16x8 v = *(const s16x8*)(k_bf + ((size_t)row << 10) + c);
  unsigned lo = 0, hi = 0;
  lo = __builtin_amdgcn_cvt_pk_fp8_f32(bf2f(v[0]) * 4.f, bf2f(v[1]) * 4.f, lo, false);
  lo = __builtin_amdgcn_cvt_pk_fp8_f32(bf2f(v[2]) * 4.f, bf2f(v[3]) * 4.f, lo, true);
  hi = __builtin_amdgcn_cvt_pk_fp8_f32(bf2f(v[4]) * 4.f, bf2f(v[5]) * 4.f, hi, false);
  hi = __builtin_amdgcn_cvt_pk_fp8_f32(bf2f(v[6]) * 4.f, bf2f(v[7]) * 4.f, hi, true);
  u32x2 o; o[0] = lo; o[1] = hi;
  *(u32x2*)(k8 + ((size_t)row << 10) + (c ^ ((row & 15) << 3))) = o;
}

// qm8[h][f][.] = q[f][.] * mixbf[h][.]  (fp8, SCALE*64 in mix; same 4-bit row-key swizzle)
__global__ void qmix8_kernel(const short* __restrict__ q_bf, const short* __restrict__ mixbf,
                             unsigned char* __restrict__ qm8) {
  int f = blockIdx.x, h = blockIdx.y;
  int c = threadIdx.x * 8;
  s16x8 qv = *(const s16x8*)(q_bf + ((size_t)f << 10) + c);
  s16x8 mv = *(const s16x8*)(mixbf + ((size_t)h << 10) + c);
  float p[8];
#pragma unroll
  for (int i = 0; i < 8; ++i) p[i] = bf2f(qv[i]) * bf2f(mv[i]);
  unsigned lo = 0, hi = 0;
  lo = __builtin_amdgcn_cvt_pk_fp8_f32(p[0], p[1], lo, false);
  lo = __builtin_amdgcn_cvt_pk_fp8_f32(p[2], p[3], lo, true);
  hi = __builtin_amdgcn_cvt_pk_fp8_f32(p[4], p[5], hi, false);
  hi = __builtin_amdgcn_cvt_pk_fp8_f32(p[6], p[7], hi, true);
  u32x2 o; o[0] = lo; o[1] = hi;
  *(u32x2*)(qm8 + (((size_t)h * 2048 + f) << 10) + (c ^ ((f & 15) << 3))) = o;
}

// ---------------- content bias (pre-scaled by SCALE_LOG2E) ----------------
__global__ void cb_kernel(const short* __restrict__ to_bf, const short* __restrict__ WcbT,
                          float* __restrict__ cbv) {
  __shared__ short Wl[16 * 1024];
  int tid = threadIdx.x;
  for (int i = tid; i < 2048; i += 256)
    ((s16x8*)Wl)[i] = ((const s16x8*)WcbT)[i];
  __syncthreads();
  int w = tid >> 6, l = tid & 63;
  int t = blockIdx.x * 4 + w;
  const s16x8* xr = (const s16x8*)(to_bf + ((size_t)t << 10) + l * 16);
  s16x8 x0 = xr[0], x1 = xr[1];
  float xf[16];
#pragma unroll
  for (int i = 0; i < 8; ++i) { xf[i] = bf2f(x0[i]); xf[8 + i] = bf2f(x1[i]); }
#pragma unroll
  for (int h = 0; h < 16; ++h) {
    const s16x8* wr_ = (const s16x8*)(Wl + h * 1024 + l * 16);
    s16x8 w0 = wr_[0], w1 = wr_[1];
    float acc = 0.f;
#pragma unroll
    for (int i = 0; i < 8; ++i) { acc += xf[i] * bf2f(w0[i]); acc += xf[8 + i] * bf2f(w1[i]); }
#pragma unroll
    for (int s = 32; s; s >>= 1) acc += __shfl_xor(acc, s);
    if (l == 0) cbv[(size_t)h * 2048 + t] = acc * SCALE_LOG2E;
  }
}

// ---------------- flash attention v7: fp8 QK^T, 128B rows, FBLK=128, TBLK=128, ts=2 ---------
// LDS 80K: qmA@0(16K [128f][128B]) qmB@16K ktA@32K(16K [128t][128B]) ktB@48K vt@64K(16K)
// 2 blocks/CU. 8 dbl-chunks (128 k-elems) per t0, dbuf, counted vmcnt. cb in regs.
// P (bf16, pi-ordered t) overlays qmB: 1KB/wave, PV in 4 quarters of 32 t.
__global__ __launch_bounds__(512, 2)
void attn_kernel(const unsigned char* __restrict__ qm8, const unsigned char* __restrict__ k8,
                 const short* __restrict__ vTs, const float* __restrict__ cbg,
                 float* __restrict__ ctxp, f32x2* __restrict__ mlb) {
  __shared__ __align__(16) char smem[81920];
  char* qmA = smem;          char* qmB = smem + 16384;
  char* ktA = smem + 32768;  char* ktB = smem + 49152;
  char* vt  = smem + 65536;
  const int f0 = blockIdx.x * 128, h = blockIdx.y, ts = blockIdx.z;
  const int tb = ts << 10;                      // 1024 t per split
  const int tid = threadIdx.x, w = tid >> 6, l = tid & 63;
  const int lr = l >> 4, lc = l & 15;
  const unsigned char* qbase = qm8 + (((size_t)h * 2048 + f0) << 10);

#define ISSUE_QK(qmb, ktb, kc, trow0)                                                     \
  do {                                                                                    \
    _Pragma("unroll") for (int i_ = 0; i_ < 2; ++i_) {                                    \
      int off_ = i_ * 8192 + tid * 16;                                                    \
      g2l16(qbase + ((size_t)(off_ >> 7) << 10) + (kc) + (off_ & 127), (qmb) + off_);     \
    }                                                                                     \
    _Pragma("unroll") for (int i_ = 0; i_ < 2; ++i_) {                                    \
      int off_ = i_ * 8192 + tid * 16;                                                    \
      g2l16(k8 + ((size_t)((trow0) + (off_ >> 7)) << 10) + (kc) + (off_ & 127),           \
            (ktb) + off_);                                                                \
    }                                                                                     \
  } while (0)

  ISSUE_QK(qmA, ktA, 0, tb);                    // prologue: dbl-chunk 0 of t0=0

  float m_run[4], l_run[4];
#pragma unroll
  for (int s2 = 0; s2 < 4; ++s2) { m_run[s2] = -1e30f; l_run[s2] = 0.f; }
  f32x4 ctx[4] = {};

  for (int t0 = 0; t0 < 1024; t0 += 128) {
    // V tile (2 ops) — lands before PV (gated by steady-state VMCNT(4)s)
#pragma unroll
    for (int i = 0; i < 2; ++i) {
      int off = i * 8192 + tid * 16;
      g2l16(vTs + ((size_t)(h * 64 + (off >> 8)) << 11) + tb + t0 + ((off & 255) >> 1),
            vt + off);
    }
    // content bias -> regs (8 vmcnt ops)
    float cbr[8];
#pragma unroll
    for (int n = 0; n < 8; ++n) cbr[n] = cbg[h * 2048 + tb + t0 + n * 16 + lc];
    f32x4 sacc[8] = {};
    for (int c = 0; c < 8; ++c) {
      char* qmb = (c & 1) ? qmB : qmA;
      char* ktb = (c & 1) ? ktB : ktA;
      if (c < 7) {
        ISSUE_QK((c & 1) ? qmA : qmB, (c & 1) ? ktA : ktB, (c + 1) * 128, tb + t0);
      } else if (t0 < 896) {
        ISSUE_QK(qmA, ktA, 0, tb + t0 + 128);
      }
      if (c == 0) { VMCNT(14); }                // newer: V2+cb8+chunk1(4)
      else if (c == 7 && t0 == 896) { VMCNT(0); }
      else { VMCNT(4); }                        // newer: next chunk only
      BARRIER();
#pragma unroll
      for (int s = 0; s < 4; ++s) {
        int xr = (s * 32 + lr * 8) ^ (lc << 3);
        long af = *(const long*)(qmb + ((w * 16 + lc) << 7) + xr);
        __builtin_amdgcn_s_setprio(1);
#pragma unroll
        for (int n = 0; n < 8; ++n) {
          long bfr = *(const long*)(ktb + ((n * 16 + lc) << 7) + xr);
          sacc[n] = MFMA8(af, bfr, sacc[n]);
        }
        __builtin_amdgcn_s_setprio(0);
      }
      BARRIER();
    }
    // ---- online softmax, exp2 domain; fp8 descale 2^-8 fused into cb add
    float pm[4] = {-1e30f, -1e30f, -1e30f, -1e30f};
#pragma unroll
    for (int n = 0; n < 8; ++n)
#pragma unroll
      for (int r = 0; r < 4; ++r) {
        float s = fmaf(sacc[n][r], 0.00390625f, cbr[n]);
        sacc[n][r] = s;
        pm[r] = fmaxf(pm[r], s);
      }
#pragma unroll
    for (int s_ = 1; s_ < 16; s_ <<= 1)
#pragma unroll
      for (int r = 0; r < 4; ++r) pm[r] = fmaxf(pm[r], __shfl_xor(pm[r], s_));
    float tsum[4];
#pragma unroll
    for (int r = 0; r < 4; ++r) {
      float mnew = fmaxf(m_run[r], pm[r]);
      float corr = exp2f(m_run[r] - mnew);
      m_run[r] = mnew; l_run[r] *= corr; tsum[r] = 0.f;
#pragma unroll
      for (int n2 = 0; n2 < 4; ++n2) ctx[n2][r] *= corr;
    }
#pragma unroll
    for (int n = 0; n < 8; ++n)
#pragma unroll
      for (int r = 0; r < 4; ++r) {
        float e = exp2f(sacc[n][r] - m_run[r]);
        sacc[n][r] = e;
        tsum[r] += e;
      }
#pragma unroll
    for (int s_ = 1; s_ < 16; s_ <<= 1)
#pragma unroll
      for (int r = 0; r < 4; ++r) tsum[r] += __shfl_xor(tsum[r], s_);
#pragma unroll
    for (int r = 0; r < 4; ++r) l_run[r] += tsum[r];
    // ---- P (paired cvt_pk, pi-ordered t, col^r swizzle) + PV in 4 quarters of 32 t
    char* ptw = qmB + (w << 10);                // 1KB/wave: [16f][64B = 32 t' bf16]
#pragma unroll
    for (int qq = 0; qq < 4; ++qq) {
      if (qq) { LGKM0(); }                      // prior quarter's reads done before overwrite
#pragma unroll
      for (int r = 0; r < 4; ++r) {
        int row = lr * 4 + r;
        unsigned pk = cvtpk(sacc[2 * qq][r], sacc[2 * qq + 1][r]);
        *(unsigned*)(ptw + (row << 6) + ((lc ^ (r << 2)) << 2)) = pk;
      }
      LGKM0();
      s16x8 paf = *(const s16x8*)(ptw + (lc << 6) + ((lr * 16) ^ ((lc & 3) << 4)));
#pragma unroll
      for (int n2 = 0; n2 < 4; ++n2) {
        s16x8 vb = *(const s16x8*)(vt + ((n2 * 16 + lc) << 8) +
                                   ((qq * 64 + lr * 16) ^ ((lc & 7) << 4)));
        ctx[n2] = MFMA(paf, vb, ctx[n2]);
      }
    }
    BARRIER();   // protect vt + qmB(P region) before next t0's staging
  }
  // ---- write partials (unnormalized ctx, m, l)
  const int pb = (h * 2 + ts) * 2048;
#pragma unroll
  for (int n2 = 0; n2 < 4; ++n2)
#pragma unroll
    for (int r = 0; r < 4; ++r) {
      int f = f0 + w * 16 + lr * 4 + r;
      ctxp[((size_t)(pb + f) << 6) + n2 * 16 + lc] = ctx[n2][r];
    }
  if (lc == 0) {
#pragma unroll
    for (int s2 = 0; s2 < 4; ++s2) {
      int f = f0 + w * 16 + lr * 4 + s2;
      f32x2 v; v[0] = m_run[s2]; v[1] = l_run[s2];
      mlb[pb + f] = v;
    }
  }
#undef ISSUE_QK
}

// ---------------- combine the two t-split partials (exp2 domain) ----------------
__global__ void combine_kernel(const float* __restrict__ ctxp, const f32x2* __restrict__ mlb,
                               short* __restrict__ ctx_bf) {
  int f = blockIdx.x, tid = threadIdx.x;
  int h = tid >> 4, d4 = (tid & 15) * 4;
  f32x2 a = mlb[(h * 2 + 0) * 2048 + f];
  f32x2 b = mlb[(h * 2 + 1) * 2048 + f];
  float m = fmaxf(a[0], b[0]);
  float e0 = exp2f(a[0] - m), e1 = exp2f(b[0] - m);
  float inv = 1.f / (a[1] * e0 + b[1] * e1);
  f32x4 c0 = *(const f32x4*)(ctxp + (((size_t)(h * 2 + 0) * 2048 + f) << 6) + d4);
  f32x4 c1 = *(const f32x4*)(ctxp + (((size_t)(h * 2 + 1) * 2048 + f) << 6) + d4);
  s16x4 o;
#pragma unroll
  for (int i = 0; i < 4; ++i) o[i] = f2bf((c0[i] * e0 + c1[i] * e1) * inv);
  *(s16x4*)(ctx_bf + ((size_t)f << 10) + h * 64 + d4) = o;
}

// ---------------- final GEMM: C f32 = ctx @ WdT + bd + resid ----------------
__global__ __launch_bounds__(256, 2)
void gemm_out(const short* __restrict__ A, const short* __restrict__ B,
              const float* __restrict__ bias, const float* __restrict__ resid,
              float* __restrict__ Cout) {
  __shared__ __align__(16) short As[128][64];
  __shared__ __align__(16) short Bs[128][64];
  int m0 = blockIdx.x * 128, n0 = blockIdx.y * 128;
  int tid = threadIdx.x;
  int w = tid >> 6, l = tid & 63;
  int wr = w >> 1, wc = w & 1;
  f32x4 acc[4][4] = {};
  for (int k0 = 0; k0 < 1024; k0 += 64) {
    __syncthreads();
#pragma unroll
    for (int i = 0; i < 4; ++i) {
      int off = i * 4096 + tid * 16;
      int r = off >> 7, cb_ = off & 127;
      g2l16(A + ((size_t)(m0 + r) << 10) + k0 + (cb_ >> 1), (short*)As + (off >> 1));
      g2l16(B + ((size_t)(n0 + r) << 10) + k0 + (cb_ >> 1), (short*)Bs + (off >> 1));
    }
    __syncthreads();
#pragma unroll
    for (int ks = 0; ks < 2; ++ks) {
      s16x8 af[4], bfr[4];
#pragma unroll
      for (int m = 0; m < 4; ++m)
        af[m] = *(const s16x8*)&As[wr * 64 + m * 16 + (l & 15)][ks * 32 + (l >> 4) * 8];
#pragma unroll
      for (int n = 0; n < 4; ++n)
        bfr[n] = *(const s16x8*)&Bs[wc * 64 + n * 16 + (l & 15)][ks * 32 + (l >> 4) * 8];
#pragma unroll
      for (int m = 0; m < 4; ++m)
#pragma unroll
        for (int n = 0; n < 4; ++n)
          acc[m][n] = MFMA(af[m], bfr[n], acc[m][n]);
    }
  }
  int lr = (l >> 4) * 4, lc = l & 15;
#pragma unroll
  for (int m = 0; m < 4; ++m)
#pragma unroll
    for (int n = 0; n < 4; ++n) {
      int row = m0 + wr * 64 + m * 16 + lr;
      int col = n0 + wc * 64 + n * 16 + lc;
      float b = bias[col];
#pragma unroll
      for (int r = 0; r < 4; ++r)
        Cout[(size_t)(row + r) * 1024 + col] = acc[m][n][r] + b + resid[(size_t)(row + r) * 1024 + col];
    }
}

// ---------------- LayerNorm (in-place) ----------------
__global__ void ln_kernel(const float* __restrict__ res, const float* __restrict__ gamma,
                          const float* __restrict__ beta, float* __restrict__ out) {
  int row = blockIdx.x, tid = threadIdx.x;
  f32x4 x = *(const f32x4*)(res + ((size_t)row << 10) + tid * 4);
  float s = x[0] + x[1] + x[2] + x[3];
  float s2 = x[0] * x[0] + x[1] * x[1] + x[2] * x[2] + x[3] * x[3];
#pragma unroll
  for (int m = 1; m < 64; m <<= 1) { s += __shfl_xor(s, m); s2 += __shfl_xor(s2, m); }
  __shared__ float red[8];
  int w = tid >> 6, l = tid & 63;
  if (l == 0) { red[w] = s; red[4 + w] = s2; }
  __syncthreads();
  s = red[0] + red[1] + red[2] + red[3];
  s2 = red[4] + red[5] + red[6] + red[7];
  float mu = s * (1.f / 1024.f);
  float var = s2 * (1.f / 1024.f) - mu * mu;
  float rstd = rsqrtf(var + 1e-5f);
  f32x4 o;
#pragma unroll
  for (int i = 0; i < 4; ++i)
    o[i] = (x[i] - mu) * rstd * gamma[tid * 4 + i] + beta[tid * 4 + i];
  *(f32x4*)(out + ((size_t)row << 10) + tid * 4) = o;
}

// ---------------- launch ----------------
extern "C" void kernel_launch(void* const* d_in, const int* in_sizes, int n_in,
                              void* d_out, int out_size, void* d_ws, size_t ws_size,
                              hipStream_t stream) {
  const float* hidden = (const float*)d_in[0];
  const int*   fpos   = (const int*)d_in[1];
  const int*   tpos   = (const int*)d_in[2];
  const float* Wq     = (const float*)d_in[3];
  const float* Wk     = (const float*)d_in[4];
  const float* Wcb    = (const float*)d_in[5];
  const float* Wv     = (const float*)d_in[6];
  const float* bv     = (const float*)d_in[7];
  const float* mixing = (const float*)d_in[8];
  const float* Wd     = (const float*)d_in[9];
  const float* bd     = (const float*)d_in[10];
  const float* gamma  = (const float*)d_in[11];
  const float* beta   = (const float*)d_in[12];

  char* p = (char*)d_ws;
  auto alloc = [&](size_t bytes) { char* r = p; p += (bytes + 255) & ~(size_t)255; return r; };
  float* from_f  = (float*)alloc((size_t)2048 * 1024 * 4);
  short* from_bf = (short*)alloc((size_t)2048 * 1024 * 2);
  short* to_bf   = (short*)alloc((size_t)2048 * 1024 * 2);
  short* WqT     = (short*)alloc((size_t)1024 * 1024 * 2);
  short* WkT     = (short*)alloc((size_t)1024 * 1024 * 2);
  short* WvT     = (short*)alloc((size_t)1024 * 1024 * 2);
  short* WdT     = (short*)alloc((size_t)1024 * 1024 * 2);
  short* WcbT    = (short*)alloc((size_t)16 * 1024 * 2);
  short* mixbf   = (short*)alloc((size_t)16 * 1024 * 2);
  short* q_bf    = (short*)alloc((size_t)2048 * 1024 * 2);
  short* k_bf    = (short*)alloc((size_t)2048 * 1024 * 2);
  short* vTs     = (short*)alloc((size_t)1024 * 2048 * 2);
  unsigned char* k8  = (unsigned char*)alloc((size_t)2048 * 1024);
  unsigned char* qm8 = (unsigned char*)alloc((size_t)16 * 2048 * 1024);
  float* cbb     = (float*)alloc((size_t)16 * 2048 * 4);
  short* ctx_bf  = (short*)alloc((size_t)2048 * 1024 * 2);
  float* ctxp    = (float*)alloc((size_t)32 * 2048 * 64 * 4);
  f32x2* mlb     = (f32x2*)alloc((size_t)32 * 2048 * 8);

  wtrans_kernel<<<dim3(16, 16, 4), 256, 0, stream>>>(Wq, Wk, Wv, Wd, WqT, WkT, WvT, WdT);
  smallconv_kernel<<<128, 256, 0, stream>>>(Wcb, mixing, WcbT, mixbf);
  gather_kernel<<<dim3(2048, 2), 256, 0, stream>>>(hidden, fpos, tpos, from_f, from_bf, to_bf);
  qkv_gemm<<<dim3(16, 8, 3), 256, 0, stream>>>(from_bf, to_bf, WqT, WkT, WvT, bv,
                                               q_bf, k_bf, vTs);
  k8_kernel<<<1024, 256, 0, stream>>>(k_bf, k8);
  cb_kernel<<<512, 256, 0, stream>>>(to_bf, WcbT, cbb);
  qmix8_kernel<<<dim3(2048, 16), 128, 0, stream>>>(q_bf, mixbf, qm8);
  attn_kernel<<<dim3(16, 16, 2), 512, 0, stream>>>(qm8, k8, vTs, cbb, ctxp, mlb);
  combine_kernel<<<2048, 256, 0, stream>>>(ctxp, mlb, ctx_bf);
  gemm_out<<<dim3(16, 8), 256, 0, stream>>>(ctx_bf, WdT, bd, from_f, (float*)d_out);
  ln_kernel<<<2048, 256, 0, stream>>>((float*)d_out, gamma, beta, (float*)d_out);
}